// Round 1
// baseline (1319.898 us; speedup 1.0000x reference)
//
#include <hip/hip_runtime.h>
#include <hip/hip_bf16.h>

typedef __attribute__((ext_vector_type(8))) short bf16x8_t;
typedef __attribute__((ext_vector_type(4))) float f32x4_t;

__device__ __forceinline__ void gll16(const void* g, void* l) {
  __builtin_amdgcn_global_load_lds((const __attribute__((address_space(1))) void*)g,
                                   (__attribute__((address_space(3))) void*)l, 16, 0, 0);
}

// ---------------- f32 -> bf16 convert ----------------
__global__ __launch_bounds__(256) void k_cvt(const float* __restrict__ in,
                                             __hip_bfloat16* __restrict__ out, int n) {
  int i = blockIdx.x * 256 + threadIdx.x;
  if (i < n) out[i] = __float2bfloat16(in[i]);
}

// ---------------- rpb[head][i][j] = table[rpi[i][j]][head] ----------------
__global__ __launch_bounds__(256) void k_rpb(const int* __restrict__ rpi,
                                             const float* __restrict__ tab,
                                             float* __restrict__ rpb) {
  int i = blockIdx.x * 256 + threadIdx.x;
  if (i < 16 * 2401) {
    int h = i / 2401, idx = i - h * 2401;
    rpb[i] = tab[rpi[idx] * 16 + h];
  }
}

// ---------------- layernorm (+optional shift+window-partition), f32 -> bf16 ----------------
template<int PERM>
__global__ __launch_bounds__(256) void k_ln(const float* __restrict__ in,
                                            const float* __restrict__ g,
                                            const float* __restrict__ bta,
                                            __hip_bfloat16* __restrict__ out) {
  int token = blockIdx.x;
  int t = threadIdx.x;
  const float2 v = ((const float2*)(in + (size_t)token * 512))[t];
  float s = v.x + v.y, sq = v.x * v.x + v.y * v.y;
  #pragma unroll
  for (int d = 1; d < 64; d <<= 1) { s += __shfl_xor(s, d); sq += __shfl_xor(sq, d); }
  __shared__ float ps[4], pq[4];
  int w = t >> 6;
  if ((t & 63) == 0) { ps[w] = s; pq[w] = sq; }
  __syncthreads();
  s  = ps[0] + ps[1] + ps[2] + ps[3];
  sq = pq[0] + pq[1] + pq[2] + pq[3];
  float mean = s * (1.f / 512.f);
  float inv = rsqrtf(sq * (1.f / 512.f) - mean * mean + 1e-5f);
  size_t dst;
  if (PERM) {
    int b = token / 3136, p = token - b * 3136;
    int i = p / 56, j = p - i * 56;
    int gi = (i + 53) % 56, gj = (j + 53) % 56;       // (i-3) mod 56
    dst = ((size_t)(((b * 64) + (gi / 7) * 8 + (gj / 7)) * 49) + (gi % 7) * 7 + (gj % 7)) * 512;
  } else {
    dst = (size_t)token * 512;
  }
  int c = t * 2;
  out[dst + c]     = __float2bfloat16((v.x - mean) * inv * g[c] + bta[c]);
  out[dst + c + 1] = __float2bfloat16((v.y - mean) * inv * g[c + 1] + bta[c + 1]);
}

// ---------------- windowed attention, one block per (window, head) ----------------
__global__ __launch_bounds__(256) void k_attn(const __hip_bfloat16* __restrict__ qkv,
                                              const float* __restrict__ rpb,
                                              const float* __restrict__ mask,
                                              __hip_bfloat16* __restrict__ o) {
  int bw = blockIdx.x, head = blockIdx.y;
  __shared__ float qs[49 * 32], ks[49 * 32], vs[49 * 32];
  __shared__ float S[49 * 49];
  int t = threadIdx.x;
  const size_t base = (size_t)bw * 49 * 1536 + head * 32;
  for (int idx = t; idx < 1568; idx += 256) {
    int n = idx >> 5, d = idx & 31;
    size_t a = base + (size_t)n * 1536 + d;
    qs[idx] = __bfloat162float(qkv[a]);
    ks[idx] = __bfloat162float(qkv[a + 512]);
    vs[idx] = __bfloat162float(qkv[a + 1024]);
  }
  __syncthreads();
  const float* rp = rpb + head * 2401;
  const float* mk = mask + (size_t)(bw & 63) * 2401;
  for (int idx = t; idx < 2401; idx += 256) {
    int i = idx / 49, j = idx - i * 49;
    const float* qq = qs + i * 32;
    const float* kk = ks + j * 32;
    float s = 0.f;
    #pragma unroll
    for (int d = 0; d < 32; ++d) s += qq[d] * kk[d];
    S[idx] = s + rp[idx] + mk[idx];
  }
  __syncthreads();
  int w = t >> 6, l = t & 63;
  for (int r = w; r < 49; r += 4) {
    float v = (l < 49) ? S[r * 49 + l] : -1e30f;
    float mx = v;
    #pragma unroll
    for (int d = 1; d < 64; d <<= 1) mx = fmaxf(mx, __shfl_xor(mx, d));
    float e = (l < 49) ? expf(v - mx) : 0.f;
    float sm = e;
    #pragma unroll
    for (int d = 1; d < 64; d <<= 1) sm += __shfl_xor(sm, d);
    if (l < 49) S[r * 49 + l] = e / sm;
  }
  __syncthreads();
  for (int idx = t; idx < 1568; idx += 256) {
    int i = idx >> 5, d = idx & 31;
    const float* pp = S + i * 49;
    const float* vv = vs + d;
    float s = 0.f;
    #pragma unroll
    for (int j = 0; j < 49; ++j) s += pp[j] * vv[j * 32];
    o[(size_t)(bw * 49 + i) * 512 + head * 32 + d] = __float2bfloat16(s);
  }
}

// ---------------- 128x128 bf16 MFMA GEMM, A[M][K] @ W[N][K]^T, templated epilogue ----------------
// EP 0: qkv  (bias, scale q cols <512, bf16 out [M][1536])
// EP 1: proj (bias, window-reverse+unshift, += x residual, f32 out)
// EP 2: mlp1 (bias, exact GELU, bf16 out [M][2048])
// EP 3: mlp2 (bias, f32 accumulate into d_out)
template<int EP>
__global__ __launch_bounds__(256) void gemm_bt(const __hip_bfloat16* __restrict__ A,
                                               const __hip_bfloat16* __restrict__ Bw,
                                               int K, int Ncols,
                                               const float* __restrict__ bias,
                                               __hip_bfloat16* __restrict__ obf,
                                               const float* __restrict__ resid,
                                               float* __restrict__ ofp) {
  __shared__ __align__(16) __hip_bfloat16 Ash[128 * 32];
  __shared__ __align__(16) __hip_bfloat16 Bsh[128 * 32];
  const int m0 = blockIdx.x * 128, n0 = blockIdx.y * 128;
  const int t = threadIdx.x, l = t & 63, w = t >> 6;
  const int wr = w >> 1, wc = w & 1;
  f32x4_t acc[4][4] = {};
  const __hip_bfloat16* Ab = A + (size_t)m0 * K;
  const __hip_bfloat16* Bb = Bw + (size_t)n0 * K;
  const int r0 = t >> 2, sg = (t & 3) * 8;   // staging: row, k-segment
  const int kq = l >> 4, rr = l & 15;

  for (int k0 = 0; k0 < K; k0 += 32) {
    gll16(Ab + (size_t)r0 * K + k0 + sg, (char*)Ash + t * 16);
    gll16(Bb + (size_t)r0 * K + k0 + sg, (char*)Bsh + t * 16);
    gll16(Ab + (size_t)(r0 + 64) * K + k0 + sg, (char*)Ash + (t + 256) * 16);
    gll16(Bb + (size_t)(r0 + 64) * K + k0 + sg, (char*)Bsh + (t + 256) * 16);
    __syncthreads();
    const bf16x8_t* Af = (const bf16x8_t*)Ash;
    const bf16x8_t* Bf = (const bf16x8_t*)Bsh;
    bf16x8_t af[4], bfr[4];
    #pragma unroll
    for (int m = 0; m < 4; ++m) af[m] = Af[(wr * 64 + m * 16 + rr) * 4 + kq];
    #pragma unroll
    for (int n = 0; n < 4; ++n) bfr[n] = Bf[(wc * 64 + n * 16 + rr) * 4 + kq];
    #pragma unroll
    for (int m = 0; m < 4; ++m)
      #pragma unroll
      for (int n = 0; n < 4; ++n)
        acc[m][n] = __builtin_amdgcn_mfma_f32_16x16x32_bf16(af[m], bfr[n], acc[m][n], 0, 0, 0);
    __syncthreads();
  }

  // C/D layout: col = lane&15, row = (lane>>4)*4 + j   [measured m89/m91]
  #pragma unroll
  for (int m = 0; m < 4; ++m) {
    #pragma unroll
    for (int n = 0; n < 4; ++n) {
      const int gcol = n0 + wc * 64 + n * 16 + rr;
      #pragma unroll
      for (int j = 0; j < 4; ++j) {
        const int grow = m0 + wr * 64 + m * 16 + kq * 4 + j;
        float v = acc[m][n][j] + bias[gcol];
        if (EP == 0) {
          if (gcol < 512) v *= 0.17677669529663687f;  // hd^-0.5
          obf[(size_t)grow * Ncols + gcol] = __float2bfloat16(v);
        } else if (EP == 1) {
          int bw = grow / 49, nn = grow - bw * 49;
          int b = bw >> 6, wi = bw & 63;
          int hh = (wi >> 3) * 7 + nn / 7 + 3;  if (hh >= 56) hh -= 56;
          int ww2 = (wi & 7) * 7 + (nn % 7) + 3; if (ww2 >= 56) ww2 -= 56;
          size_t tok = (size_t)b * 3136 + hh * 56 + ww2;
          ofp[tok * 512 + gcol] = resid[tok * 512 + gcol] + v;
        } else if (EP == 2) {
          float u = 0.5f * v * (1.f + erff(v * 0.70710678118f));
          obf[(size_t)grow * Ncols + gcol] = __float2bfloat16(u);
        } else {
          ofp[(size_t)grow * 512 + gcol] += v;
        }
      }
    }
  }
}

extern "C" void kernel_launch(void* const* d_in, const int* in_sizes, int n_in,
                              void* d_out, int out_size, void* d_ws, size_t ws_size,
                              hipStream_t stream) {
  const float* x      = (const float*)d_in[0];
  const int*   rpi    = (const int*)  d_in[1];
  const float* amask  = (const float*)d_in[2];
  const float* n1g    = (const float*)d_in[3];
  const float* n1b    = (const float*)d_in[4];
  const float* qkv_w  = (const float*)d_in[5];
  const float* qkv_b  = (const float*)d_in[6];
  const float* proj_w = (const float*)d_in[7];
  const float* proj_b = (const float*)d_in[8];
  const float* rpb_t  = (const float*)d_in[9];
  const float* n2g    = (const float*)d_in[10];
  const float* n2b    = (const float*)d_in[11];
  const float* w1     = (const float*)d_in[12];
  const float* b1     = (const float*)d_in[13];
  const float* w2     = (const float*)d_in[14];
  const float* b2     = (const float*)d_in[15];
  float* out = (float*)d_out;

  char* ws = (char*)d_ws;
  const size_t M = 50176;
  const size_t szA = M * 2048 * 2;          // region A: xw -> o -> m
  const size_t szB = M * 1536 * 2;          // region B: qkv -> h2
  const size_t offB = szA;
  const size_t offR = offB + szB;
  const size_t offW = offR + (size_t)16 * 2401 * 4;
  __hip_bfloat16* bufA = (__hip_bfloat16*)(ws);
  __hip_bfloat16* bufB = (__hip_bfloat16*)(ws + offB);
  float* rpb = (float*)(ws + offR);
  __hip_bfloat16* wqkv  = (__hip_bfloat16*)(ws + offW);
  __hip_bfloat16* wproj = wqkv + 786432;
  __hip_bfloat16* wm1   = wproj + 262144;
  __hip_bfloat16* wm2   = wm1 + 1048576;

  k_cvt<<<3072, 256, 0, stream>>>(qkv_w, wqkv, 786432);
  k_cvt<<<1024, 256, 0, stream>>>(proj_w, wproj, 262144);
  k_cvt<<<4096, 256, 0, stream>>>(w1, wm1, 1048576);
  k_cvt<<<4096, 256, 0, stream>>>(w2, wm2, 1048576);
  k_rpb<<<151, 256, 0, stream>>>(rpi, rpb_t, rpb);

  // LN1 + shift + window partition -> bufA (bf16, [50176][512])
  k_ln<1><<<50176, 256, 0, stream>>>(x, n1g, n1b, bufA);
  // QKV: bufA @ wqkv^T -> bufB (bf16, [50176][1536], q pre-scaled)
  gemm_bt<0><<<dim3(392, 12), 256, 0, stream>>>(bufA, wqkv, 512, 1536, qkv_b, bufB, nullptr, nullptr);
  // attention -> bufA (bf16, [50176][512])
  k_attn<<<dim3(1024, 16), 256, 0, stream>>>(bufB, rpb, amask, bufA);
  // proj + window reverse + unshift + residual -> d_out (f32)
  gemm_bt<1><<<dim3(392, 4), 256, 0, stream>>>(bufA, wproj, 512, 512, proj_b, nullptr, x, out);
  // LN2 -> bufB (bf16, [50176][512])
  k_ln<0><<<50176, 256, 0, stream>>>(out, n2g, n2b, bufB);
  // MLP1 + GELU -> bufA (bf16, [50176][2048])
  gemm_bt<2><<<dim3(392, 16), 256, 0, stream>>>(bufB, wm1, 512, 2048, b1, bufA, nullptr, nullptr);
  // MLP2 + residual accumulate -> d_out
  gemm_bt<3><<<dim3(392, 4), 256, 0, stream>>>(bufA, wm2, 2048, 512, b2, nullptr, nullptr, out);
}

// Round 3
// 893.230 us; speedup vs baseline: 1.4777x; 1.4777x over previous
//
#include <hip/hip_runtime.h>
#include <hip/hip_bf16.h>

typedef __attribute__((ext_vector_type(8))) short bf16x8_t;
typedef __attribute__((ext_vector_type(4))) float f32x4_t;

__device__ __forceinline__ void gll16(const void* g, void* l) {
  __builtin_amdgcn_global_load_lds((const __attribute__((address_space(1))) void*)g,
                                   (__attribute__((address_space(3))) void*)l, 16, 0, 0);
}

// ---------------- f32 -> bf16 convert ----------------
__global__ __launch_bounds__(256) void k_cvt(const float* __restrict__ in,
                                             __hip_bfloat16* __restrict__ out, int n) {
  int i = blockIdx.x * 256 + threadIdx.x;
  if (i < n) out[i] = __float2bfloat16(in[i]);
}

// ---------------- cmbp: rpb+mask packed in MFMA C-fragment order ----------------
// layout: [(w6*16+h)][tile=tm*4+tn][lane][jj]  (f32), padding cells = -1e9
__global__ __launch_bounds__(256) void k_cmb(const int* __restrict__ rpi,
                                             const float* __restrict__ tab,
                                             const float* __restrict__ mask,
                                             float* __restrict__ cmbp) {
  int idx = blockIdx.x * 256 + threadIdx.x;   // < 64*16*16*256 = 4194304
  int jj = idx & 3, lane = (idx >> 2) & 63, tile = (idx >> 8) & 15;
  int h = (idx >> 12) & 15, w6 = idx >> 16;
  int r = (tile >> 2) * 16 + (lane >> 4) * 4 + jj;
  int c = (tile & 3) * 16 + (lane & 15);
  float v = -1e9f;
  if (r < 49 && c < 49) v = tab[rpi[r * 49 + c] * 16 + h] + mask[w6 * 2401 + r * 49 + c];
  cmbp[idx] = v;
}

// ---------------- layernorm (+optional shift+window-partition), f32 -> bf16 ----------------
template<int PERM>
__global__ __launch_bounds__(256) void k_ln(const float* __restrict__ in,
                                            const float* __restrict__ g,
                                            const float* __restrict__ bta,
                                            __hip_bfloat16* __restrict__ out) {
  int token = blockIdx.x;
  int t = threadIdx.x;
  const float2 v = ((const float2*)(in + (size_t)token * 512))[t];
  float s = v.x + v.y, sq = v.x * v.x + v.y * v.y;
  #pragma unroll
  for (int d = 1; d < 64; d <<= 1) { s += __shfl_xor(s, d); sq += __shfl_xor(sq, d); }
  __shared__ float ps[4], pq[4];
  int w = t >> 6;
  if ((t & 63) == 0) { ps[w] = s; pq[w] = sq; }
  __syncthreads();
  s  = ps[0] + ps[1] + ps[2] + ps[3];
  sq = pq[0] + pq[1] + pq[2] + pq[3];
  float mean = s * (1.f / 512.f);
  float inv = rsqrtf(sq * (1.f / 512.f) - mean * mean + 1e-5f);
  size_t dst;
  if (PERM) {
    int b = token / 3136, p = token - b * 3136;
    int i = p / 56, j = p - i * 56;
    int gi = (i + 53) % 56, gj = (j + 53) % 56;       // (i-3) mod 56
    dst = ((size_t)(((b * 64) + (gi / 7) * 8 + (gj / 7)) * 49) + (gi % 7) * 7 + (gj % 7)) * 512;
  } else {
    dst = (size_t)token * 512;
  }
  int c = t * 2;
  out[dst + c]     = __float2bfloat16((v.x - mean) * inv * g[c] + bta[c]);
  out[dst + c + 1] = __float2bfloat16((v.y - mean) * inv * g[c + 1] + bta[c + 1]);
}

// ---------------- MFMA windowed attention: one wave per (window, head) ----------------
// S(64x64 padded) = QK^T + cmbp(C-in);  in-register softmax;  O = P V via LDS-staged P, V^T.
__global__ __launch_bounds__(256) void k_attn(const __hip_bfloat16* __restrict__ qkv,
                                              const float* __restrict__ cmbp,
                                              __hip_bfloat16* __restrict__ o) {
  __shared__ __align__(16) __hip_bfloat16 vt_all[4 * 32 * 72];
  __shared__ __align__(16) __hip_bfloat16 P_all[4 * 64 * 72];
  const int t = threadIdx.x, l = t & 63, w = t >> 6;
  const int bw = blockIdx.x;
  const int head = blockIdx.y * 4 + w;
  const int rr = l & 15, g = l >> 4;
  __hip_bfloat16* vt = vt_all + w * (32 * 72);
  __hip_bfloat16* P  = P_all  + w * (64 * 72);
  const __hip_bfloat16* base = qkv + (size_t)bw * 49 * 1536 + head * 32;
  const bf16x8_t zero8 = {};

  // zero vt padding columns 48..63 (avoid NaN-garbage x 0 in PV MFMA)
  { int d = l >> 1, sg = (l & 1) * 8;
    *(bf16x8_t*)(vt + d * 72 + 48 + sg) = zero8; }
  __builtin_amdgcn_sched_barrier(0);
  // stage V transposed: vt[d][j] = v[j][d]   (49 rows x 4 eight-elem segments = 196)
  #pragma unroll
  for (int it = 0; it < 4; ++it) {
    int idx = l + it * 64;
    if (idx < 196) {
      int j = idx >> 2, sg = (idx & 3) * 8;
      bf16x8_t vv = *(const bf16x8_t*)(base + 1024 + (size_t)j * 1536 + sg);
      #pragma unroll
      for (int s2 = 0; s2 < 8; ++s2) vt[(sg + s2) * 72 + j] = ((__hip_bfloat16*)&vv)[s2];
    }
  }
  // Q/K fragments direct from global (A/B frag: lane holds row rr, k-seg g*8..)
  bf16x8_t aq[4], bk[4];
  #pragma unroll
  for (int m = 0; m < 4; ++m) {
    int row = m * 16 + rr;
    aq[m] = (row < 49) ? *(const bf16x8_t*)(base + (size_t)row * 1536 + g * 8) : zero8;
    bk[m] = (row < 49) ? *(const bf16x8_t*)(base + 512 + (size_t)row * 1536 + g * 8) : zero8;
  }
  // S = QK^T with cmbp as C-in
  const float4* cp = (const float4*)(cmbp + (size_t)((bw & 63) * 16 + head) * 4096);
  f32x4_t S[4][4];
  #pragma unroll
  for (int tm = 0; tm < 4; ++tm)
    #pragma unroll
    for (int tn = 0; tn < 4; ++tn) {
      float4 cv = cp[(tm * 4 + tn) * 64 + l];
      f32x4_t c0 = { cv.x, cv.y, cv.z, cv.w };
      S[tm][tn] = __builtin_amdgcn_mfma_f32_16x16x32_bf16(aq[tm], bk[tn], c0, 0, 0, 0);
    }
  // in-register softmax: rows r = tm*16 + g*4 + jj, cols spread over 16-lane group x tn
  float sm[4][4];
  #pragma unroll
  for (int tm = 0; tm < 4; ++tm) {
    #pragma unroll
    for (int jj = 0; jj < 4; ++jj) {
      float v = fmaxf(fmaxf(S[tm][0][jj], S[tm][1][jj]), fmaxf(S[tm][2][jj], S[tm][3][jj]));
      v = fmaxf(v, __shfl_xor(v, 1));
      v = fmaxf(v, __shfl_xor(v, 2));
      v = fmaxf(v, __shfl_xor(v, 4));
      v = fmaxf(v, __shfl_xor(v, 8));
      float s = 0.f;
      #pragma unroll
      for (int tn = 0; tn < 4; ++tn) {
        float e = __expf(S[tm][tn][jj] - v);
        S[tm][tn][jj] = e;
        s += e;
      }
      s += __shfl_xor(s, 1); s += __shfl_xor(s, 2); s += __shfl_xor(s, 4); s += __shfl_xor(s, 8);
      sm[tm][jj] = s;
    }
  }
  // write P (bf16, unnormalized; padded cols are exactly 0 via -1e9 bias)
  #pragma unroll
  for (int tm = 0; tm < 4; ++tm)
    #pragma unroll
    for (int tn = 0; tn < 4; ++tn)
      #pragma unroll
      for (int jj = 0; jj < 4; ++jj)
        P[(tm * 16 + g * 4 + jj) * 72 + tn * 16 + rr] = __float2bfloat16(S[tm][tn][jj]);

  // O = P V  (K = 64 over token dim j)
  f32x4_t O[4][2] = {};
  #pragma unroll
  for (int ks = 0; ks < 2; ++ks) {
    bf16x8_t pa[4], vb[2];
    #pragma unroll
    for (int tm = 0; tm < 4; ++tm)
      pa[tm] = *(const bf16x8_t*)(P + (tm * 16 + rr) * 72 + ks * 32 + g * 8);
    #pragma unroll
    for (int tn = 0; tn < 2; ++tn)
      vb[tn] = *(const bf16x8_t*)(vt + (tn * 16 + rr) * 72 + ks * 32 + g * 8);
    #pragma unroll
    for (int tm = 0; tm < 4; ++tm)
      #pragma unroll
      for (int tn = 0; tn < 2; ++tn)
        O[tm][tn] = __builtin_amdgcn_mfma_f32_16x16x32_bf16(pa[tm], vb[tn], O[tm][tn], 0, 0, 0);
  }
  // epilogue: normalize by row-sum, store rows < 49
  #pragma unroll
  for (int tm = 0; tm < 4; ++tm) {
    #pragma unroll
    for (int jj = 0; jj < 4; ++jj) {
      int r = tm * 16 + g * 4 + jj;
      if (r < 49) {
        float rcp = 1.f / sm[tm][jj];
        size_t ob = ((size_t)bw * 49 + r) * 512 + head * 32;
        o[ob + rr]      = __float2bfloat16(O[tm][0][jj] * rcp);
        o[ob + 16 + rr] = __float2bfloat16(O[tm][1][jj] * rcp);
      }
    }
  }
}

// ---------------- 128x128 bf16 MFMA GEMM, A[M][K] @ W[N][K]^T, templated epilogue ----------------
template<int EP>
__global__ __launch_bounds__(256) void gemm_bt(const __hip_bfloat16* __restrict__ A,
                                               const __hip_bfloat16* __restrict__ Bw,
                                               int K, int Ncols,
                                               const float* __restrict__ bias,
                                               __hip_bfloat16* __restrict__ obf,
                                               const float* __restrict__ resid,
                                               float* __restrict__ ofp) {
  __shared__ __align__(16) __hip_bfloat16 Ash[128 * 32];
  __shared__ __align__(16) __hip_bfloat16 Bsh[128 * 32];
  const int m0 = blockIdx.x * 128, n0 = blockIdx.y * 128;
  const int t = threadIdx.x, l = t & 63, w = t >> 6;
  const int wr = w >> 1, wc = w & 1;
  f32x4_t acc[4][4] = {};
  const __hip_bfloat16* Ab = A + (size_t)m0 * K;
  const __hip_bfloat16* Bb = Bw + (size_t)n0 * K;
  const int r0 = t >> 2, sg = (t & 3) * 8;
  const int kq = l >> 4, rr = l & 15;

  for (int k0 = 0; k0 < K; k0 += 32) {
    gll16(Ab + (size_t)r0 * K + k0 + sg, (char*)Ash + t * 16);
    gll16(Bb + (size_t)r0 * K + k0 + sg, (char*)Bsh + t * 16);
    gll16(Ab + (size_t)(r0 + 64) * K + k0 + sg, (char*)Ash + (t + 256) * 16);
    gll16(Bb + (size_t)(r0 + 64) * K + k0 + sg, (char*)Bsh + (t + 256) * 16);
    __syncthreads();
    const bf16x8_t* Af = (const bf16x8_t*)Ash;
    const bf16x8_t* Bf = (const bf16x8_t*)Bsh;
    bf16x8_t af[4], bfr[4];
    #pragma unroll
    for (int m = 0; m < 4; ++m) af[m] = Af[(wr * 64 + m * 16 + rr) * 4 + kq];
    #pragma unroll
    for (int n = 0; n < 4; ++n) bfr[n] = Bf[(wc * 64 + n * 16 + rr) * 4 + kq];
    #pragma unroll
    for (int m = 0; m < 4; ++m)
      #pragma unroll
      for (int n = 0; n < 4; ++n)
        acc[m][n] = __builtin_amdgcn_mfma_f32_16x16x32_bf16(af[m], bfr[n], acc[m][n], 0, 0, 0);
    __syncthreads();
  }

  #pragma unroll
  for (int m = 0; m < 4; ++m) {
    #pragma unroll
    for (int n = 0; n < 4; ++n) {
      const int gcol = n0 + wc * 64 + n * 16 + rr;
      #pragma unroll
      for (int j = 0; j < 4; ++j) {
        const int grow = m0 + wr * 64 + m * 16 + kq * 4 + j;
        float v = acc[m][n][j] + bias[gcol];
        if (EP == 0) {
          if (gcol < 512) v *= 0.17677669529663687f;  // hd^-0.5
          obf[(size_t)grow * Ncols + gcol] = __float2bfloat16(v);
        } else if (EP == 1) {
          int bw = grow / 49, nn = grow - bw * 49;
          int b = bw >> 6, wi = bw & 63;
          int hh = (wi >> 3) * 7 + nn / 7 + 3;  if (hh >= 56) hh -= 56;
          int ww2 = (wi & 7) * 7 + (nn % 7) + 3; if (ww2 >= 56) ww2 -= 56;
          size_t tok = (size_t)b * 3136 + hh * 56 + ww2;
          ofp[tok * 512 + gcol] = resid[tok * 512 + gcol] + v;
        } else if (EP == 2) {
          float u = 0.5f * v * (1.f + erff(v * 0.70710678118f));
          obf[(size_t)grow * Ncols + gcol] = __float2bfloat16(u);
        } else {
          ofp[(size_t)grow * 512 + gcol] += v;
        }
      }
    }
  }
}

extern "C" void kernel_launch(void* const* d_in, const int* in_sizes, int n_in,
                              void* d_out, int out_size, void* d_ws, size_t ws_size,
                              hipStream_t stream) {
  const float* x      = (const float*)d_in[0];
  const int*   rpi    = (const int*)  d_in[1];
  const float* amask  = (const float*)d_in[2];
  const float* n1g    = (const float*)d_in[3];
  const float* n1b    = (const float*)d_in[4];
  const float* qkv_w  = (const float*)d_in[5];
  const float* qkv_b  = (const float*)d_in[6];
  const float* proj_w = (const float*)d_in[7];
  const float* proj_b = (const float*)d_in[8];
  const float* rpb_t  = (const float*)d_in[9];
  const float* n2g    = (const float*)d_in[10];
  const float* n2b    = (const float*)d_in[11];
  const float* w1     = (const float*)d_in[12];
  const float* b1     = (const float*)d_in[13];
  const float* w2     = (const float*)d_in[14];
  const float* b2     = (const float*)d_in[15];
  float* out = (float*)d_out;

  char* ws = (char*)d_ws;
  const size_t M = 50176;
  const size_t szA = M * 2048 * 2;          // region A: xw -> o -> m   (tail reused for cmbp)
  const size_t szB = M * 1536 * 2;          // region B: qkv -> h2
  const size_t offB = szA;
  const size_t offW = offB + szB;
  __hip_bfloat16* bufA = (__hip_bfloat16*)(ws);
  __hip_bfloat16* bufB = (__hip_bfloat16*)(ws + offB);
  __hip_bfloat16* wqkv  = (__hip_bfloat16*)(ws + offW);
  __hip_bfloat16* wproj = wqkv + 786432;
  __hip_bfloat16* wm1   = wproj + 262144;
  __hip_bfloat16* wm2   = wm1 + 1048576;
  // cmbp lives in the tail of bufA: only MLP1's [M][2048] output (after attention) touches it
  float* cmbp = (float*)(ws + szA - (size_t)4194304 * 4);

  k_cvt<<<3072, 256, 0, stream>>>(qkv_w, wqkv, 786432);
  k_cvt<<<1024, 256, 0, stream>>>(proj_w, wproj, 262144);
  k_cvt<<<4096, 256, 0, stream>>>(w1, wm1, 1048576);
  k_cvt<<<4096, 256, 0, stream>>>(w2, wm2, 1048576);
  k_cmb<<<16384, 256, 0, stream>>>(rpi, rpb_t, amask, cmbp);

  // LN1 + shift + window partition -> bufA (bf16, [50176][512])
  k_ln<1><<<50176, 256, 0, stream>>>(x, n1g, n1b, bufA);
  // QKV: bufA @ wqkv^T -> bufB (bf16, [50176][1536], q pre-scaled)
  gemm_bt<0><<<dim3(392, 12), 256, 0, stream>>>(bufA, wqkv, 512, 1536, qkv_b, bufB, nullptr, nullptr);
  // MFMA attention -> bufA (bf16, [50176][512])
  k_attn<<<dim3(1024, 4), 256, 0, stream>>>(bufB, cmbp, bufA);
  // proj + window reverse + unshift + residual -> d_out (f32)
  gemm_bt<1><<<dim3(392, 4), 256, 0, stream>>>(bufA, wproj, 512, 512, proj_b, nullptr, x, out);
  // LN2 -> bufB (bf16, [50176][512])
  k_ln<0><<<50176, 256, 0, stream>>>(out, n2g, n2b, bufB);
  // MLP1 + GELU -> bufA (bf16, [50176][2048])
  gemm_bt<2><<<dim3(392, 16), 256, 0, stream>>>(bufB, wm1, 512, 2048, b1, bufA, nullptr, nullptr);
  // MLP2 + residual accumulate -> d_out
  gemm_bt<3><<<dim3(392, 4), 256, 0, stream>>>(bufA, wm2, 2048, 512, b2, nullptr, nullptr, out);
}

// Round 4
// 826.313 us; speedup vs baseline: 1.5973x; 1.0810x over previous
//
#include <hip/hip_runtime.h>
#include <hip/hip_bf16.h>

typedef __attribute__((ext_vector_type(8))) short bf16x8_t;
typedef __attribute__((ext_vector_type(4))) float f32x4_t;

__device__ __forceinline__ void gll16(const void* g, void* l) {
  __builtin_amdgcn_global_load_lds((const __attribute__((address_space(1))) void*)g,
                                   (__attribute__((address_space(3))) void*)l, 16, 0, 0);
}

// ---------------- f32 -> bf16 convert ----------------
__global__ __launch_bounds__(256) void k_cvt(const float* __restrict__ in,
                                             __hip_bfloat16* __restrict__ out, int n) {
  int i = blockIdx.x * 256 + threadIdx.x;
  if (i < n) out[i] = __float2bfloat16(in[i]);
}

// ---------------- cmbp: rpb+mask packed in MFMA C-fragment order ----------------
__global__ __launch_bounds__(256) void k_cmb(const int* __restrict__ rpi,
                                             const float* __restrict__ tab,
                                             const float* __restrict__ mask,
                                             float* __restrict__ cmbp) {
  int idx = blockIdx.x * 256 + threadIdx.x;   // < 64*16*16*256 = 4194304
  int jj = idx & 3, lane = (idx >> 2) & 63, tile = (idx >> 8) & 15;
  int h = (idx >> 12) & 15, w6 = idx >> 16;
  int r = (tile >> 2) * 16 + (lane >> 4) * 4 + jj;
  int c = (tile & 3) * 16 + (lane & 15);
  float v = -1e9f;
  if (r < 49 && c < 49) v = tab[rpi[r * 49 + c] * 16 + h] + mask[w6 * 2401 + r * 49 + c];
  cmbp[idx] = v;
}

// ---------------- layernorm (+optional shift+window-partition), f32 -> bf16 ----------------
template<int PERM>
__global__ __launch_bounds__(256) void k_ln(const float* __restrict__ in,
                                            const float* __restrict__ g,
                                            const float* __restrict__ bta,
                                            __hip_bfloat16* __restrict__ out) {
  int token = blockIdx.x;
  int t = threadIdx.x;
  const float2 v = ((const float2*)(in + (size_t)token * 512))[t];
  float s = v.x + v.y, sq = v.x * v.x + v.y * v.y;
  #pragma unroll
  for (int d = 1; d < 64; d <<= 1) { s += __shfl_xor(s, d); sq += __shfl_xor(sq, d); }
  __shared__ float ps[4], pq[4];
  int w = t >> 6;
  if ((t & 63) == 0) { ps[w] = s; pq[w] = sq; }
  __syncthreads();
  s  = ps[0] + ps[1] + ps[2] + ps[3];
  sq = pq[0] + pq[1] + pq[2] + pq[3];
  float mean = s * (1.f / 512.f);
  float inv = rsqrtf(sq * (1.f / 512.f) - mean * mean + 1e-5f);
  size_t dst;
  if (PERM) {
    int b = token / 3136, p = token - b * 3136;
    int i = p / 56, j = p - i * 56;
    int gi = (i + 53) % 56, gj = (j + 53) % 56;       // (i-3) mod 56
    dst = ((size_t)(((b * 64) + (gi / 7) * 8 + (gj / 7)) * 49) + (gi % 7) * 7 + (gj % 7)) * 512;
  } else {
    dst = (size_t)token * 512;
  }
  int c = t * 2;
  out[dst + c]     = __float2bfloat16((v.x - mean) * inv * g[c] + bta[c]);
  out[dst + c + 1] = __float2bfloat16((v.y - mean) * inv * g[c + 1] + bta[c + 1]);
}

// ---------------- MFMA windowed attention: one wave per (window, head) ----------------
__global__ __launch_bounds__(256) void k_attn(const __hip_bfloat16* __restrict__ qkv,
                                              const float* __restrict__ cmbp,
                                              __hip_bfloat16* __restrict__ o) {
  __shared__ __align__(16) __hip_bfloat16 vt_all[4 * 32 * 72];
  __shared__ __align__(16) __hip_bfloat16 P_all[4 * 64 * 72];
  const int t = threadIdx.x, l = t & 63, w = t >> 6;
  const int bw = blockIdx.x;
  const int head = blockIdx.y * 4 + w;
  const int rr = l & 15, g = l >> 4;
  __hip_bfloat16* vt = vt_all + w * (32 * 72);
  __hip_bfloat16* P  = P_all  + w * (64 * 72);
  const __hip_bfloat16* base = qkv + (size_t)bw * 49 * 1536 + head * 32;
  const bf16x8_t zero8 = {};

  { int d = l >> 1, sg = (l & 1) * 8;
    *(bf16x8_t*)(vt + d * 72 + 48 + sg) = zero8; }
  __builtin_amdgcn_sched_barrier(0);
  #pragma unroll
  for (int it = 0; it < 4; ++it) {
    int idx = l + it * 64;
    if (idx < 196) {
      int j = idx >> 2, sg = (idx & 3) * 8;
      bf16x8_t vv = *(const bf16x8_t*)(base + 1024 + (size_t)j * 1536 + sg);
      #pragma unroll
      for (int s2 = 0; s2 < 8; ++s2) vt[(sg + s2) * 72 + j] = ((__hip_bfloat16*)&vv)[s2];
    }
  }
  bf16x8_t aq[4], bk[4];
  #pragma unroll
  for (int m = 0; m < 4; ++m) {
    int row = m * 16 + rr;
    aq[m] = (row < 49) ? *(const bf16x8_t*)(base + (size_t)row * 1536 + g * 8) : zero8;
    bk[m] = (row < 49) ? *(const bf16x8_t*)(base + 512 + (size_t)row * 1536 + g * 8) : zero8;
  }
  const float4* cp = (const float4*)(cmbp + (size_t)((bw & 63) * 16 + head) * 4096);
  f32x4_t S[4][4];
  #pragma unroll
  for (int tm = 0; tm < 4; ++tm)
    #pragma unroll
    for (int tn = 0; tn < 4; ++tn) {
      float4 cv = cp[(tm * 4 + tn) * 64 + l];
      f32x4_t c0 = { cv.x, cv.y, cv.z, cv.w };
      S[tm][tn] = __builtin_amdgcn_mfma_f32_16x16x32_bf16(aq[tm], bk[tn], c0, 0, 0, 0);
    }
  float sm[4][4];
  #pragma unroll
  for (int tm = 0; tm < 4; ++tm) {
    #pragma unroll
    for (int jj = 0; jj < 4; ++jj) {
      float v = fmaxf(fmaxf(S[tm][0][jj], S[tm][1][jj]), fmaxf(S[tm][2][jj], S[tm][3][jj]));
      v = fmaxf(v, __shfl_xor(v, 1));
      v = fmaxf(v, __shfl_xor(v, 2));
      v = fmaxf(v, __shfl_xor(v, 4));
      v = fmaxf(v, __shfl_xor(v, 8));
      float s = 0.f;
      #pragma unroll
      for (int tn = 0; tn < 4; ++tn) {
        float e = __expf(S[tm][tn][jj] - v);
        S[tm][tn][jj] = e;
        s += e;
      }
      s += __shfl_xor(s, 1); s += __shfl_xor(s, 2); s += __shfl_xor(s, 4); s += __shfl_xor(s, 8);
      sm[tm][jj] = s;
    }
  }
  #pragma unroll
  for (int tm = 0; tm < 4; ++tm)
    #pragma unroll
    for (int tn = 0; tn < 4; ++tn)
      #pragma unroll
      for (int jj = 0; jj < 4; ++jj)
        P[(tm * 16 + g * 4 + jj) * 72 + tn * 16 + rr] = __float2bfloat16(S[tm][tn][jj]);

  f32x4_t O[4][2] = {};
  #pragma unroll
  for (int ks = 0; ks < 2; ++ks) {
    bf16x8_t pa[4], vb[2];
    #pragma unroll
    for (int tm = 0; tm < 4; ++tm)
      pa[tm] = *(const bf16x8_t*)(P + (tm * 16 + rr) * 72 + ks * 32 + g * 8);
    #pragma unroll
    for (int tn = 0; tn < 2; ++tn)
      vb[tn] = *(const bf16x8_t*)(vt + (tn * 16 + rr) * 72 + ks * 32 + g * 8);
    #pragma unroll
    for (int tm = 0; tm < 4; ++tm)
      #pragma unroll
      for (int tn = 0; tn < 2; ++tn)
        O[tm][tn] = __builtin_amdgcn_mfma_f32_16x16x32_bf16(pa[tm], vb[tn], O[tm][tn], 0, 0, 0);
  }
  #pragma unroll
  for (int tm = 0; tm < 4; ++tm) {
    #pragma unroll
    for (int jj = 0; jj < 4; ++jj) {
      int r = tm * 16 + g * 4 + jj;
      if (r < 49) {
        float rcp = 1.f / sm[tm][jj];
        size_t ob = ((size_t)bw * 49 + r) * 512 + head * 32;
        o[ob + rr]      = __float2bfloat16(O[tm][0][jj] * rcp);
        o[ob + 16 + rr] = __float2bfloat16(O[tm][1][jj] * rcp);
      }
    }
  }
}

// ---------------- 256x256 deep-pipelined bf16 GEMM, A[M][K] @ W[N][K]^T ----------------
// 8 waves (2M x 4N), BK=64, double-buffered LDS with 16x32-subtile swizzle (T2),
// issue-early staging (one half-tile per phase), 1 barrier per K-tile, setprio (T5),
// bijective XCD block swizzle (T1).  EP epilogues as before.
template<int EP>
__global__ __launch_bounds__(512, 2) void gemm256(const __hip_bfloat16* __restrict__ A,
                                                  const __hip_bfloat16* __restrict__ Bw,
                                                  int K, int Ncols, int nNB,
                                                  const float* __restrict__ bias,
                                                  __hip_bfloat16* __restrict__ obf,
                                                  const float* __restrict__ resid,
                                                  float* __restrict__ ofp) {
  __shared__ __align__(16) char LDS[131072];  // A: [2buf][2half][16KB], B at +65536 same
  // T1: bijective XCD swizzle (m204), bx-major decode for A-panel L2 reuse
  const int nwg = gridDim.x, orig = blockIdx.x;
  const int q8 = nwg >> 3, r8 = nwg & 7;
  const int xcd = orig & 7, lin = orig >> 3;
  const int wgid = (xcd < r8 ? xcd * (q8 + 1) : r8 * (q8 + 1) + (xcd - r8) * q8) + lin;
  const int bx = wgid / nNB, by = wgid - bx * nNB;
  const int m0 = bx * 256, n0 = by * 256;
  const int t = threadIdx.x, l = t & 63, w = t >> 6;
  const int wr = w >> 2, wc = w & 3;
  const int rr = l & 15, kq = l >> 4;

  // staging source decode (pre-swizzled global so linear LDS dest yields subtile+swz layout)
  int r0, c0, r1, c1;
  { int d = t * 16; int sub = d >> 10, wr_ = (d & 1023) >> 6, wc_ = d & 63;
    int cb = wc_ ^ ((wr_ & 8) << 2); r0 = (sub >> 1) * 16 + wr_; c0 = (sub & 1) * 32 + (cb >> 1); }
  { int d = t * 16 + 8192; int sub = d >> 10, wr_ = (d & 1023) >> 6, wc_ = d & 63;
    int cb = wc_ ^ ((wr_ & 8) << 2); r1 = (sub >> 1) * 16 + wr_; c1 = (sub & 1) * 32 + (cb >> 1); }
  const size_t o0 = (size_t)r0 * K + c0, o1 = (size_t)r1 * K + c1;
  const __hip_bfloat16* gA = A + (size_t)m0 * K;
  const __hip_bfloat16* gB = Bw + (size_t)n0 * K;

  auto stageA = [&](int buf, int h, int k0) {
    char* dst = LDS + buf * 32768 + h * 16384;
    const __hip_bfloat16* s = gA + (size_t)h * 128 * K + k0;
    gll16(s + o0, dst + t * 16);
    gll16(s + o1, dst + t * 16 + 8192);
  };
  auto stageB = [&](int buf, int h, int k0) {
    char* dst = LDS + 65536 + buf * 32768 + h * 16384;
    const __hip_bfloat16* s = gB + (size_t)h * 128 * K + k0;
    gll16(s + o0, dst + t * 16);
    gll16(s + o1, dst + t * 16 + 8192);
  };

  const char *baseA = nullptr, *baseB = nullptr;
  auto ldA = [&](bf16x8_t (&ar)[4][2], int mq) {
    #pragma unroll
    for (int m = 0; m < 4; ++m)
      #pragma unroll
      for (int ks = 0; ks < 2; ++ks) {
        int r = mq * 64 + m * 16 + rr;
        int off = ((r >> 4) * 2 + ks) * 1024 + (r & 15) * 64 + ((kq * 16) ^ ((r & 8) << 2));
        ar[m][ks] = *(const bf16x8_t*)(baseA + off);
      }
  };
  auto ldB = [&](bf16x8_t (&br)[2][2], int nq) {
    #pragma unroll
    for (int n = 0; n < 2; ++n)
      #pragma unroll
      for (int ks = 0; ks < 2; ++ks) {
        int r = (wc & 1) * 64 + nq * 32 + n * 16 + rr;
        int off = ((r >> 4) * 2 + ks) * 1024 + (r & 15) * 64 + ((kq * 16) ^ ((r & 8) << 2));
        br[n][ks] = *(const bf16x8_t*)(baseB + off);
      }
  };

  f32x4_t a00[4][2] = {}, a01[4][2] = {}, a10[4][2] = {}, a11[4][2] = {};
  auto mma = [&](f32x4_t (&ac)[4][2], bf16x8_t (&ar)[4][2], bf16x8_t (&br)[2][2]) {
    __builtin_amdgcn_s_setprio(1);
    #pragma unroll
    for (int m = 0; m < 4; ++m)
      #pragma unroll
      for (int n = 0; n < 2; ++n)
        #pragma unroll
        for (int ks = 0; ks < 2; ++ks)
          ac[m][n] = __builtin_amdgcn_mfma_f32_16x16x32_bf16(ar[m][ks], br[n][ks], ac[m][n], 0, 0, 0);
    __builtin_amdgcn_s_setprio(0);
  };

  // prologue: stage K-tile 0 into buf 0
  stageA(0, 0, 0); stageA(0, 1, 0); stageB(0, 0, 0); stageB(0, 1, 0);
  __syncthreads();

  const int NT = K >> 6;
  int cur = 0;
  for (int kt = 0; kt < NT; ++kt) {
    const int nxt = cur ^ 1, k1 = (kt + 1) << 6;
    const bool st = (kt + 1 < NT);
    baseA = LDS + cur * 32768 + wr * 16384;
    baseB = LDS + 65536 + cur * 32768 + (wc >> 1) * 16384;
    bf16x8_t ar[4][2], br0[2][2], br1[2][2];
    if (st) stageA(nxt, 0, k1);          // P0
    ldA(ar, 0); ldB(br0, 0);
    mma(a00, ar, br0);
    if (st) stageA(nxt, 1, k1);          // P1
    ldB(br1, 1);
    mma(a01, ar, br1);
    if (st) stageB(nxt, 0, k1);          // P2
    ldA(ar, 1);
    mma(a11, ar, br1);
    if (st) stageB(nxt, 1, k1);          // P3
    mma(a10, ar, br0);
    __syncthreads();                      // compiler emits vmcnt(0)+lgkmcnt(0) drain here
    cur = nxt;
  }

  // epilogue: C/D layout col=lane&15, row=(lane>>4)*4+j
  auto epi = [&](f32x4_t (&ac)[4][2], int mq, int nq) {
    #pragma unroll
    for (int m = 0; m < 4; ++m) {
      #pragma unroll
      for (int n = 0; n < 2; ++n) {
        const int gcol = n0 + wc * 64 + nq * 32 + n * 16 + rr;
        #pragma unroll
        for (int j = 0; j < 4; ++j) {
          const int grow = m0 + wr * 128 + mq * 64 + m * 16 + kq * 4 + j;
          float v = ac[m][n][j] + bias[gcol];
          if (EP == 0) {
            if (gcol < 512) v *= 0.17677669529663687f;  // hd^-0.5
            obf[(size_t)grow * Ncols + gcol] = __float2bfloat16(v);
          } else if (EP == 1) {
            int bw = grow / 49, nn = grow - bw * 49;
            int b = bw >> 6, wi = bw & 63;
            int hh = (wi >> 3) * 7 + nn / 7 + 3;  if (hh >= 56) hh -= 56;
            int ww2 = (wi & 7) * 7 + (nn % 7) + 3; if (ww2 >= 56) ww2 -= 56;
            size_t tok = (size_t)b * 3136 + hh * 56 + ww2;
            ofp[tok * 512 + gcol] = resid[tok * 512 + gcol] + v;
          } else if (EP == 2) {
            float u = 0.5f * v * (1.f + erff(v * 0.70710678118f));
            obf[(size_t)grow * Ncols + gcol] = __float2bfloat16(u);
          } else {
            ofp[(size_t)grow * 512 + gcol] += v;
          }
        }
      }
    }
  };
  epi(a00, 0, 0); epi(a01, 0, 1); epi(a10, 1, 0); epi(a11, 1, 1);
}

extern "C" void kernel_launch(void* const* d_in, const int* in_sizes, int n_in,
                              void* d_out, int out_size, void* d_ws, size_t ws_size,
                              hipStream_t stream) {
  const float* x      = (const float*)d_in[0];
  const int*   rpi    = (const int*)  d_in[1];
  const float* amask  = (const float*)d_in[2];
  const float* n1g    = (const float*)d_in[3];
  const float* n1b    = (const float*)d_in[4];
  const float* qkv_w  = (const float*)d_in[5];
  const float* qkv_b  = (const float*)d_in[6];
  const float* proj_w = (const float*)d_in[7];
  const float* proj_b = (const float*)d_in[8];
  const float* rpb_t  = (const float*)d_in[9];
  const float* n2g    = (const float*)d_in[10];
  const float* n2b    = (const float*)d_in[11];
  const float* w1     = (const float*)d_in[12];
  const float* b1     = (const float*)d_in[13];
  const float* w2     = (const float*)d_in[14];
  const float* b2     = (const float*)d_in[15];
  float* out = (float*)d_out;

  char* ws = (char*)d_ws;
  const size_t M = 50176;
  const size_t szA = M * 2048 * 2;          // region A: xw -> o -> m   (tail reused for cmbp)
  const size_t szB = M * 1536 * 2;          // region B: qkv -> h2
  const size_t offB = szA;
  const size_t offW = offB + szB;
  __hip_bfloat16* bufA = (__hip_bfloat16*)(ws);
  __hip_bfloat16* bufB = (__hip_bfloat16*)(ws + offB);
  __hip_bfloat16* wqkv  = (__hip_bfloat16*)(ws + offW);
  __hip_bfloat16* wproj = wqkv + 786432;
  __hip_bfloat16* wm1   = wproj + 262144;
  __hip_bfloat16* wm2   = wm1 + 1048576;
  float* cmbp = (float*)(ws + szA - (size_t)4194304 * 4);

  k_cvt<<<3072, 256, 0, stream>>>(qkv_w, wqkv, 786432);
  k_cvt<<<1024, 256, 0, stream>>>(proj_w, wproj, 262144);
  k_cvt<<<4096, 256, 0, stream>>>(w1, wm1, 1048576);
  k_cvt<<<4096, 256, 0, stream>>>(w2, wm2, 1048576);
  k_cmb<<<16384, 256, 0, stream>>>(rpi, rpb_t, amask, cmbp);

  // LN1 + shift + window partition -> bufA (bf16, [50176][512])
  k_ln<1><<<50176, 256, 0, stream>>>(x, n1g, n1b, bufA);
  // QKV: bufA @ wqkv^T -> bufB (bf16, [50176][1536], q pre-scaled)
  gemm256<0><<<196 * 6, 512, 0, stream>>>(bufA, wqkv, 512, 1536, 6, qkv_b, bufB, nullptr, nullptr);
  // MFMA attention -> bufA (bf16, [50176][512])
  k_attn<<<dim3(1024, 4), 256, 0, stream>>>(bufB, cmbp, bufA);
  // proj + window reverse + unshift + residual -> d_out (f32)
  gemm256<1><<<196 * 2, 512, 0, stream>>>(bufA, wproj, 512, 512, 2, proj_b, nullptr, x, out);
  // LN2 -> bufB (bf16, [50176][512])
  k_ln<0><<<50176, 256, 0, stream>>>(out, n2g, n2b, bufB);
  // MLP1 + GELU -> bufA (bf16, [50176][2048])
  gemm256<2><<<196 * 8, 512, 0, stream>>>(bufB, wm1, 512, 2048, 8, b1, bufA, nullptr, nullptr);
  // MLP2 + residual accumulate -> d_out
  gemm256<3><<<196 * 2, 512, 0, stream>>>(bufA, wm2, 2048, 512, 2, b2, nullptr, nullptr, out);
}